// Round 1
// baseline (50043.192 us; speedup 1.0000x reference)
//
#include <hip/hip_runtime.h>
#include <cfloat>

#define NROWS 65536
#define DIM   256
#define KCB   4096

#define BM 128
#define BK 128
#define BD 32
#define LSTR 36   // LDS row stride in floats (pad: 36 % 32 banks -> stride-4 banks, 2-way max)

// ---------------- row squared-norms (4 rows per 256-thread block) ----------------
__global__ void norms_kernel(const float* __restrict__ x, float* __restrict__ out) {
  const int row  = blockIdx.x * 4 + (threadIdx.x >> 6);
  const int lane = threadIdx.x & 63;
  const float4 v = ((const float4*)(x + (size_t)row * DIM))[lane];
  float s = v.x * v.x + v.y * v.y + v.z * v.z + v.w * v.w;
  #pragma unroll
  for (int off = 32; off > 0; off >>= 1) s += __shfl_down(s, off);
  if (lane == 0) out[row] = s;
}

// ---------------- fused distance GEMM + argmin ----------------
// dist[n][k] = fp32(fp32(z_norm[n] + e_norm[k]) - 2*dot(z[n], cb[k]))
// argmin with first-index tie-break, replicating numpy fp32 semantics.
__launch_bounds__(256, 2)
__global__ void argmin_kernel(const float* __restrict__ z,
                              const float* __restrict__ cb,
                              const float* __restrict__ znorm,
                              const float* __restrict__ enorm,
                              int* __restrict__ idx_out) {
  __shared__ float z_s[BM * LSTR];
  __shared__ float e_s[BK * LSTR];
  __shared__ float zn_s[BM];

  const int tid = threadIdx.x;
  const int tx = tid & 15;   // k dimension
  const int ty = tid >> 4;   // row dimension
  const int rbase = blockIdx.x * BM;

  if (tid < BM) zn_s[tid] = znorm[rbase + tid];

  float bestv[8];
  int   besti[8];
  #pragma unroll
  for (int i = 0; i < 8; ++i) { bestv[i] = FLT_MAX; besti[i] = 0; }

  for (int kc = 0; kc < KCB; kc += BK) {
    float acc[8][8];
    #pragma unroll
    for (int i = 0; i < 8; ++i)
      #pragma unroll
      for (int j = 0; j < 8; ++j) acc[i][j] = 0.0f;

    for (int dc = 0; dc < DIM; dc += BD) {
      __syncthreads();
      // stage z-tile [128 x 32] and e-tile [128 x 32] (4 float4 each per thread)
      #pragma unroll
      for (int p = 0; p < 4; ++p) {
        const int el = p * 256 + tid;
        const int r  = el >> 3;
        const int c4 = (el & 7) * 4;
        *(float4*)(&z_s[r * LSTR + c4]) =
            *(const float4*)(z + (size_t)(rbase + r) * DIM + dc + c4);
        *(float4*)(&e_s[r * LSTR + c4]) =
            *(const float4*)(cb + (size_t)(kc + r) * DIM + dc + c4);
      }
      __syncthreads();

      #pragma unroll
      for (int dd = 0; dd < BD; dd += 4) {
        float4 a[8], b[8];
        #pragma unroll
        for (int i = 0; i < 8; ++i)
          a[i] = *(const float4*)(&z_s[(ty + 16 * i) * LSTR + dd]);
        #pragma unroll
        for (int j = 0; j < 8; ++j)
          b[j] = *(const float4*)(&e_s[(tx + 16 * j) * LSTR + dd]);
        #pragma unroll
        for (int i = 0; i < 8; ++i)
          #pragma unroll
          for (int j = 0; j < 8; ++j)
            acc[i][j] += a[i].x * b[j].x + a[i].y * b[j].y +
                         a[i].z * b[j].z + a[i].w * b[j].w;
      }
    }

    // per-k-chunk argmin update (ascending k, strict <, lexicographic reduce)
    #pragma unroll
    for (int i = 0; i < 8; ++i) {
      const float zn = zn_s[ty + 16 * i];
      float lv = FLT_MAX; int li = 0;
      #pragma unroll
      for (int j = 0; j < 8; ++j) {
        const int k = kc + tx + 16 * j;
        const float t1 = zn + enorm[k];          // fp32 round (matches np broadcast add)
        const float dist = t1 - 2.0f * acc[i][j]; // fp32 round (2*acc exact)
        if (dist < lv) { lv = dist; li = k; }
      }
      #pragma unroll
      for (int off = 1; off < 16; off <<= 1) {
        const float ov = __shfl_xor(lv, off);
        const int   oi = __shfl_xor(li, off);
        if (ov < lv || (ov == lv && oi < li)) { lv = ov; li = oi; }
      }
      if (lv < bestv[i] || (lv == bestv[i] && li < besti[i])) {
        bestv[i] = lv; besti[i] = li;
      }
    }
  }

  if (tx == 0) {
    #pragma unroll
    for (int i = 0; i < 8; ++i) idx_out[rbase + ty + 16 * i] = besti[i];
  }
}

// ---------------- gather z_q, straight-through output, loss partials ----------------
__global__ void gather_kernel(const float* __restrict__ z,
                              const float* __restrict__ cb,
                              const int* __restrict__ idx,
                              float* __restrict__ out_zq,
                              float* __restrict__ out_idx,
                              float* __restrict__ partials) {
  const int row  = blockIdx.x * 4 + (threadIdx.x >> 6);
  const int lane = threadIdx.x & 63;
  const int k = idx[row];
  const float4 zv = ((const float4*)(z  + (size_t)row * DIM))[lane];
  const float4 ev = ((const float4*)(cb + (size_t)k   * DIM))[lane];
  float4 d, st;
  d.x = ev.x - zv.x; d.y = ev.y - zv.y; d.z = ev.z - zv.z; d.w = ev.w - zv.w;
  st.x = zv.x + d.x; st.y = zv.y + d.y; st.z = zv.z + d.z; st.w = zv.w + d.w;
  ((float4*)(out_zq + (size_t)row * DIM))[lane] = st;
  if (lane == 0) out_idx[row] = (float)k;
  float s = d.x * d.x + d.y * d.y + d.z * d.z + d.w * d.w;
  #pragma unroll
  for (int off = 32; off > 0; off >>= 1) s += __shfl_down(s, off);
  __shared__ float ps[4];
  if (lane == 0) ps[threadIdx.x >> 6] = s;
  __syncthreads();
  if (threadIdx.x == 0)
    partials[blockIdx.x] = (ps[0] + ps[1]) + (ps[2] + ps[3]);
}

// ---------------- loss finalize ----------------
__global__ void loss_kernel(const float* __restrict__ partials,
                            float* __restrict__ out_loss) {
  float s = 0.0f;
  for (int i = threadIdx.x; i < NROWS / 4; i += 256) s += partials[i];
  #pragma unroll
  for (int off = 32; off > 0; off >>= 1) s += __shfl_down(s, off);
  __shared__ float ps[4];
  if ((threadIdx.x & 63) == 0) ps[threadIdx.x >> 6] = s;
  __syncthreads();
  if (threadIdx.x == 0)
    *out_loss = 0.25f * (((ps[0] + ps[1]) + (ps[2] + ps[3])) *
                         (1.0f / (float)((size_t)NROWS * DIM)));
}

extern "C" void kernel_launch(void* const* d_in, const int* in_sizes, int n_in,
                              void* d_out, int out_size, void* d_ws, size_t ws_size,
                              hipStream_t stream) {
  const float* z  = (const float*)d_in[0];   // [65536, 256]
  const float* cb = (const float*)d_in[1];   // [4096, 256]

  float* ws       = (float*)d_ws;
  float* enorm    = ws;                         // 4096
  float* znorm    = ws + KCB;                   // 65536
  int*   idx      = (int*)(ws + KCB + NROWS);   // 65536
  float* partials = ws + KCB + 2 * NROWS;       // 16384

  float* out_zq   = (float*)d_out;
  float* out_idx  = out_zq + (size_t)NROWS * DIM;
  float* out_loss = out_idx + NROWS;

  hipLaunchKernelGGL(norms_kernel, dim3(KCB / 4), dim3(256), 0, stream, cb, enorm);
  hipLaunchKernelGGL(norms_kernel, dim3(NROWS / 4), dim3(256), 0, stream, z, znorm);
  hipLaunchKernelGGL(argmin_kernel, dim3(NROWS / BM), dim3(256), 0, stream,
                     z, cb, znorm, enorm, idx);
  hipLaunchKernelGGL(gather_kernel, dim3(NROWS / 4), dim3(256), 0, stream,
                     z, cb, idx, out_zq, out_idx, partials);
  hipLaunchKernelGGL(loss_kernel, dim3(1), dim3(256), 0, stream, partials, out_loss);
}